// Round 2
// baseline (282.988 us; speedup 1.0000x reference)
//
#include <hip/hip_runtime.h>
#include <cstdint>
#include <cstddef>

// ---------------------------------------------------------------------------
// MultiHeadAttention forward, MI355X/gfx950.
// Pipeline: cvt(fp32->bf16) -> fused QKV GEMM (MFMA) -> flash attention
// (MFMA QK^T / PV, online softmax) -> output projection GEMM (fp32 out).
// All matmuls: v_mfma_f32_16x16x32_bf16, fp32 accumulation.
// MFMA layouts (verified in guide, m89/m91/m120):
//   A-frag: lane l holds A[m = l&15][k = (l>>4)*8 + j], j=0..7
//   B-frag: lane l holds Bt[n = l&15][k = (l>>4)*8 + j]   (Bt = [N][K] row-major)
//   C/D   : lane l, reg r holds D[m = (l>>4)*4 + r][n = l&15]
// R1 fix: online-softmax denominator must be rescaled: l = l*alpha + rowsum.
// ---------------------------------------------------------------------------

#define D_MODEL 1024
#define NHEAD   16
#define HDIM    64
#define BATCH   2
#define SEQ     2048
#define BT      (BATCH * SEQ)   // 4096

typedef __bf16 bf16;
typedef __bf16 bf16x8 __attribute__((ext_vector_type(8)));
typedef __bf16 bf16x4 __attribute__((ext_vector_type(4)));
typedef float  floatx4 __attribute__((ext_vector_type(4)));

#define MFMA16(a, b, c) __builtin_amdgcn_mfma_f32_16x16x32_bf16((a), (b), (c), 0, 0, 0)

// async global->LDS, 16B per lane. LDS dest = wave-uniform base + lane*16.
__device__ __forceinline__ void async_cp16(const bf16* g, bf16* l) {
  __builtin_amdgcn_global_load_lds(
      (__attribute__((address_space(1))) void*)(g),
      (__attribute__((address_space(3))) void*)(l), 16, 0, 0);
}

// ---------------------------------------------------------------------------
// fp32 -> bf16 conversion for q,k,v and the 4 weight matrices.
// blockIdx.y selects the tensor.
// ---------------------------------------------------------------------------
__global__ __launch_bounds__(256) void cvt7(
    const float* __restrict__ s0, const float* __restrict__ s1,
    const float* __restrict__ s2, const float* __restrict__ s3,
    const float* __restrict__ s4, const float* __restrict__ s5,
    const float* __restrict__ s6,
    bf16* __restrict__ d0, bf16* __restrict__ d1, bf16* __restrict__ d2,
    bf16* __restrict__ d3, bf16* __restrict__ d4, bf16* __restrict__ d5,
    bf16* __restrict__ d6)
{
  const float* src; bf16* dst; int n4;
  switch (blockIdx.y) {
    case 0:  src = s0; dst = d0; n4 = (BT * D_MODEL) / 4; break;
    case 1:  src = s1; dst = d1; n4 = (BT * D_MODEL) / 4; break;
    case 2:  src = s2; dst = d2; n4 = (BT * D_MODEL) / 4; break;
    case 3:  src = s3; dst = d3; n4 = (D_MODEL * D_MODEL) / 4; break;
    case 4:  src = s4; dst = d4; n4 = (D_MODEL * D_MODEL) / 4; break;
    case 5:  src = s5; dst = d5; n4 = (D_MODEL * D_MODEL) / 4; break;
    default: src = s6; dst = d6; n4 = (D_MODEL * D_MODEL) / 4; break;
  }
  int stride = gridDim.x * blockDim.x;
  for (int i = blockIdx.x * blockDim.x + threadIdx.x; i < n4; i += stride) {
    float4 f = ((const float4*)src)[i];
    bf16x4 h;
    h[0] = (bf16)f.x; h[1] = (bf16)f.y; h[2] = (bf16)f.z; h[3] = (bf16)f.w;
    ((bf16x4*)dst)[i] = h;
  }
}

// ---------------------------------------------------------------------------
// 128x128-tile GEMM core, K=1024, BK=32 (m97 structure).
// C[m][n] = sum_k A[m][k] * W[n][k];  A:[4096][1024] bf16, W:[1024][1024] bf16.
// 256 threads = 4 waves in 2x2; each wave computes 64x64 via 4x4 MFMA tiles.
// ---------------------------------------------------------------------------
__device__ __forceinline__ void gemm128_core(
    const bf16* __restrict__ A, const bf16* __restrict__ W,
    int m0, int n0, bf16* As, bf16* Bs, floatx4 acc[4][4])
{
  const int t = threadIdx.x;
  const int l = t & 63, w = t >> 6;
  const int quad = l >> 4, lr = l & 15;
  const int wm = (w >> 1) * 64, wn = (w & 1) * 64;

  floatx4 z = {0.f, 0.f, 0.f, 0.f};
#pragma unroll
  for (int i = 0; i < 4; i++)
#pragma unroll
    for (int j = 0; j < 4; j++) acc[i][j] = z;

  for (int kt = 0; kt < 1024; kt += 32) {
    __syncthreads();   // prior iter's LDS reads complete before overwrite
    // Stage A-tile [128][32] and B-tile [128][32]: 512 x 16B chunks each.
    // chunk c: row = c>>2, ci = c&3; lane l of wave w writes LDS chunk base+l.
#pragma unroll
    for (int i = 0; i < 2; i++) {
      int c = i * 256 + t;
      int row = c >> 2, ci = c & 3;
      async_cp16(A + (size_t)(m0 + row) * 1024 + kt + ci * 8,
                 As + (i * 256 + w * 64) * 8);
      async_cp16(W + (size_t)(n0 + row) * 1024 + kt + ci * 8,
                 Bs + (i * 256 + w * 64) * 8);
    }
    __syncthreads();   // compiler drains vmcnt(0) before s_barrier

    bf16x8 af[4], bfr[4];
#pragma unroll
    for (int i = 0; i < 4; i++) {
      af[i]  = *(const bf16x8*)(As + (wm + i * 16 + lr) * 32 + quad * 8);
      bfr[i] = *(const bf16x8*)(Bs + (wn + i * 16 + lr) * 32 + quad * 8);
    }
#pragma unroll
    for (int i = 0; i < 4; i++)
#pragma unroll
      for (int j = 0; j < 4; j++)
        acc[i][j] = MFMA16(af[i], bfr[j], acc[i][j]);
  }
}

// ---------------------------------------------------------------------------
// Fused QKV projection. blockIdx.z in {0,1,2} selects (q,Wq)->qh, (k,Wk)->kh,
// (v,Wv)->vt. qh,kh stored [B*H][T][64]; v stored TRANSPOSED [B*H][64][T]
// so the attention PV B-operand reads contiguous frags.
// ---------------------------------------------------------------------------
__global__ __launch_bounds__(256) void qkv_gemm(
    const bf16* __restrict__ qb, const bf16* __restrict__ kb, const bf16* __restrict__ vb,
    const bf16* __restrict__ wq, const bf16* __restrict__ wk, const bf16* __restrict__ wv,
    const float* __restrict__ biasq, const float* __restrict__ biask, const float* __restrict__ biasv,
    bf16* __restrict__ qh, bf16* __restrict__ kh, bf16* __restrict__ vt)
{
  __shared__ bf16 As[128 * 32];
  __shared__ bf16 Bs[128 * 32];
  const int zid = blockIdx.z;
  const bf16* A = (zid == 0) ? qb : ((zid == 1) ? kb : vb);
  const bf16* W = (zid == 0) ? wq : ((zid == 1) ? wk : wv);
  const float* bias = (zid == 0) ? biasq : ((zid == 1) ? biask : biasv);
  const int m0 = blockIdx.x * 128, n0 = blockIdx.y * 128;

  floatx4 acc[4][4];
  gemm128_core(A, W, m0, n0, As, Bs, acc);

  const int t = threadIdx.x, l = t & 63, w = t >> 6;
  const int quad = l >> 4, lr = l & 15;
  const int wm = (w >> 1) * 64, wn = (w & 1) * 64;

  if (zid < 2) {
    bf16* out = (zid == 0) ? qh : kh;
#pragma unroll
    for (int i = 0; i < 4; i++) {
      int mbase = m0 + wm + i * 16 + quad * 4;       // global row (b*2048+t)
      int b  = mbase >> 11;
      int tq = mbase & 2047;
#pragma unroll
      for (int j = 0; j < 4; j++) {
        int n = n0 + wn + j * 16 + lr;               // e = h*64 + dh
        float bv = bias[n];
        int h = n >> 6, dh = n & 63;
        bf16* p = out + ((size_t)((b * NHEAD + h) * SEQ + tq)) * HDIM + dh;
#pragma unroll
        for (int r = 0; r < 4; r++)
          p[(size_t)r * HDIM] = (bf16)(acc[i][j][r] + bv);
      }
    }
  } else {
    // v, transposed: vt[(b*NHEAD+h)][dh][t]; 4 consecutive t per lane -> 8B store
#pragma unroll
    for (int i = 0; i < 4; i++) {
      int mbase = m0 + wm + i * 16 + quad * 4;
      int b  = mbase >> 11;
      int tq = mbase & 2047;
#pragma unroll
      for (int j = 0; j < 4; j++) {
        int n = n0 + wn + j * 16 + lr;
        float bv = bias[n];
        int h = n >> 6, dh = n & 63;
        bf16x4 pk;
#pragma unroll
        for (int r = 0; r < 4; r++) pk[r] = (bf16)(acc[i][j][r] + bv);
        *(bf16x4*)(vt + ((size_t)((b * NHEAD + h) * HDIM + dh)) * SEQ + tq) = pk;
      }
    }
  }
}

// ---------------------------------------------------------------------------
// Flash attention. Grid: (T/128, B*H). Block 256 = 4 waves; wave w owns
// 32 query rows. Per 128-key tile: stage K [128][64+8] and V^T [64][128+8]
// (pad -> 2-way bank aliasing only, free per m136), QK^T via MFMA, online
// softmax in C-layout regs, P through a per-wave LDS buffer (C-layout ->
// A-layout transform), PV via MFMA.
// ---------------------------------------------------------------------------
__global__ __launch_bounds__(256) void attn_fused(
    const bf16* __restrict__ qh, const bf16* __restrict__ kh,
    const bf16* __restrict__ vt, bf16* __restrict__ attn)
{
  __shared__ bf16 Ks[128 * 72];     // 18432 B, row stride 144 B
  __shared__ bf16 Vts[64 * 136];    // 17408 B, row stride 272 B
  __shared__ bf16 Pbuf[4 * 32 * 40];// 10240 B, row stride 80 B (=5*16, aligned)

  const int t = threadIdx.x, l = t & 63, w = t >> 6;
  const int quad = l >> 4, lr = l & 15;
  const int bh = blockIdx.y;
  const int qt0 = blockIdx.x * 128;
  const bf16* qg = qh + (size_t)bh * SEQ * HDIM;
  const bf16* kg = kh + (size_t)bh * SEQ * HDIM;
  const bf16* vg = vt + (size_t)bh * HDIM * SEQ;

  // Q A-frags for this wave's 32 rows, K=64 -> 2 frags per 16-row tile.
  bf16x8 qf[2][2];
#pragma unroll
  for (int mi = 0; mi < 2; mi++)
#pragma unroll
    for (int ko = 0; ko < 2; ko++)
      qf[mi][ko] = *(const bf16x8*)(qg + (size_t)(qt0 + w * 32 + mi * 16 + lr) * HDIM
                                    + ko * 32 + quad * 8);

  floatx4 zz = {0.f, 0.f, 0.f, 0.f};
  floatx4 Oacc[2][4];
#pragma unroll
  for (int mi = 0; mi < 2; mi++)
#pragma unroll
    for (int di = 0; di < 4; di++) Oacc[mi][di] = zz;
  float mrow[2][4], lrow[2][4];
#pragma unroll
  for (int mi = 0; mi < 2; mi++)
#pragma unroll
    for (int r = 0; r < 4; r++) { mrow[mi][r] = -3.0e38f; lrow[mi][r] = 0.f; }

  const float scale = 0.125f;   // 1/sqrt(64)

  for (int kt0 = 0; kt0 < SEQ; kt0 += 128) {
    __syncthreads();
    // Stage K-tile (128 keys x 64) and V^T-tile (64 x 128 keys), 16B/lane.
#pragma unroll
    for (int i = 0; i < 4; i++) {
      int c = t + 256 * i;
      { int row = c >> 3, ci = c & 7;   // K: 8 chunks/row
        *(int4*)(Ks + row * 72 + ci * 8) =
            *(const int4*)(kg + (size_t)(kt0 + row) * HDIM + ci * 8); }
      { int row = c >> 4, ci = c & 15;  // V^T: 16 chunks/row
        *(int4*)(Vts + row * 136 + ci * 8) =
            *(const int4*)(vg + (size_t)row * SEQ + kt0 + ci * 8); }
    }
    __syncthreads();

    // S = Q K^T for this wave's 32 rows x 128 keys (2 x 8 MFMA tiles)
    floatx4 s[2][8];
#pragma unroll
    for (int ni = 0; ni < 8; ni++) {
      bf16x8 k0 = *(const bf16x8*)(Ks + (ni * 16 + lr) * 72 + quad * 8);
      bf16x8 k1 = *(const bf16x8*)(Ks + (ni * 16 + lr) * 72 + 32 + quad * 8);
#pragma unroll
      for (int mi = 0; mi < 2; mi++) {
        floatx4 a = zz;
        a = MFMA16(qf[mi][0], k0, a);
        a = MFMA16(qf[mi][1], k1, a);
        s[mi][ni] = a;
      }
    }

    // Online softmax stats (rows m = quad*4 + r; reduce across the 16 lanes
    // of the row with xor-shuffles 1,2,4,8 — stays within the quad group).
    float mnew[2][4], rsum[2][4], alpha[2][4];
#pragma unroll
    for (int mi = 0; mi < 2; mi++) {
      float rmax[4];
#pragma unroll
      for (int r = 0; r < 4; r++) rmax[r] = s[mi][0][r];
#pragma unroll
      for (int ni = 1; ni < 8; ni++)
#pragma unroll
        for (int r = 0; r < 4; r++) rmax[r] = fmaxf(rmax[r], s[mi][ni][r]);
      for (int mk = 1; mk < 16; mk <<= 1)
#pragma unroll
        for (int r = 0; r < 4; r++)
          rmax[r] = fmaxf(rmax[r], __shfl_xor(rmax[r], mk, 64));
#pragma unroll
      for (int r = 0; r < 4; r++) {
        mnew[mi][r] = fmaxf(mrow[mi][r], rmax[r] * scale);
        alpha[mi][r] = __expf(mrow[mi][r] - mnew[mi][r]);
        mrow[mi][r] = mnew[mi][r];
        rsum[mi][r] = 0.f;
      }
#pragma unroll
      for (int di = 0; di < 4; di++)
#pragma unroll
        for (int r = 0; r < 4; r++) Oacc[mi][di][r] *= alpha[mi][r];
    }

    // P streaming: per kk (32-key slice), write P into per-wave buffer
    // (C-layout scatter), then one PV MFMA step (A-layout frags).
#pragma unroll
    for (int kk = 0; kk < 4; kk++) {
#pragma unroll
      for (int mi = 0; mi < 2; mi++)
#pragma unroll
        for (int jj = 0; jj < 2; jj++) {
          int ni = kk * 2 + jj;
#pragma unroll
          for (int r = 0; r < 4; r++) {
            float pv = __expf(s[mi][ni][r] * scale - mnew[mi][r]);
            rsum[mi][r] += pv;
            Pbuf[(w * 32 + mi * 16 + quad * 4 + r) * 40 + jj * 16 + lr] = (bf16)pv;
          }
        }
      bf16x8 pa[2];
#pragma unroll
      for (int mi = 0; mi < 2; mi++)
        pa[mi] = *(const bf16x8*)(Pbuf + (w * 32 + mi * 16 + lr) * 40 + quad * 8);
#pragma unroll
      for (int di = 0; di < 4; di++) {
        bf16x8 vfr = *(const bf16x8*)(Vts + (di * 16 + lr) * 136 + kk * 32 + quad * 8);
#pragma unroll
        for (int mi = 0; mi < 2; mi++)
          Oacc[mi][di] = MFMA16(pa[mi], vfr, Oacc[mi][di]);
      }
    }

    // fold this tile's row sums into l (with the alpha rescale — R1 fix)
#pragma unroll
    for (int mi = 0; mi < 2; mi++) {
      for (int mk = 1; mk < 16; mk <<= 1)
#pragma unroll
        for (int r = 0; r < 4; r++)
          rsum[mi][r] += __shfl_xor(rsum[mi][r], mk, 64);
#pragma unroll
      for (int r = 0; r < 4; r++)
        lrow[mi][r] = lrow[mi][r] * alpha[mi][r] + rsum[mi][r];
    }
  }

  // Epilogue: O /= l, store to attn [B][T][D_MODEL] at column h*64+d.
  const int b = bh >> 4, h = bh & 15;
#pragma unroll
  for (int mi = 0; mi < 2; mi++) {
    float inv[4];
#pragma unroll
    for (int r = 0; r < 4; r++) inv[r] = 1.0f / lrow[mi][r];
#pragma unroll
    for (int di = 0; di < 4; di++)
#pragma unroll
      for (int r = 0; r < 4; r++) {
        int tq = qt0 + w * 32 + mi * 16 + quad * 4 + r;
        attn[((size_t)b * SEQ + tq) * D_MODEL + h * HDIM + di * 16 + lr] =
            (bf16)(Oacc[mi][di][r] * inv[r]);
      }
  }
}

// ---------------------------------------------------------------------------
// Output projection: out = attn @ Wo^T + bo, fp32 output.
// ---------------------------------------------------------------------------
__global__ __launch_bounds__(256) void oproj_gemm(
    const bf16* __restrict__ attn, const bf16* __restrict__ wo,
    const float* __restrict__ bo, float* __restrict__ out)
{
  __shared__ bf16 As[128 * 32];
  __shared__ bf16 Bs[128 * 32];
  const int m0 = blockIdx.x * 128, n0 = blockIdx.y * 128;

  floatx4 acc[4][4];
  gemm128_core(attn, wo, m0, n0, As, Bs, acc);

  const int t = threadIdx.x, l = t & 63, w = t >> 6;
  const int quad = l >> 4, lr = l & 15;
  const int wm = (w >> 1) * 64, wn = (w & 1) * 64;

#pragma unroll
  for (int i = 0; i < 4; i++) {
    int m = m0 + wm + i * 16 + quad * 4;
#pragma unroll
    for (int j = 0; j < 4; j++) {
      int n = n0 + wn + j * 16 + lr;
      float bv = bo[n];
      float* p = out + (size_t)m * D_MODEL + n;
#pragma unroll
      for (int r = 0; r < 4; r++)
        p[(size_t)r * D_MODEL] = acc[i][j][r] + bv;
    }
  }
}

// ---------------------------------------------------------------------------
extern "C" void kernel_launch(void* const* d_in, const int* in_sizes, int n_in,
                              void* d_out, int out_size, void* d_ws, size_t ws_size,
                              hipStream_t stream)
{
  const float* q  = (const float*)d_in[0];
  const float* k  = (const float*)d_in[1];
  const float* v  = (const float*)d_in[2];
  const float* Wq = (const float*)d_in[3];
  const float* bq = (const float*)d_in[4];
  const float* Wk = (const float*)d_in[5];
  const float* bk = (const float*)d_in[6];
  const float* Wv = (const float*)d_in[7];
  const float* bv = (const float*)d_in[8];
  const float* Wo = (const float*)d_in[9];
  const float* bo = (const float*)d_in[10];

  const size_t NQ = (size_t)BT * D_MODEL;        // 4194304
  const size_t NW = (size_t)D_MODEL * D_MODEL;   // 1048576

  bf16* p = (bf16*)d_ws;
  bf16* qb   = p; p += NQ;
  bf16* kb   = p; p += NQ;
  bf16* vb   = p; p += NQ;
  bf16* wqb  = p; p += NW;
  bf16* wkb  = p; p += NW;
  bf16* wvb  = p; p += NW;
  bf16* wob  = p; p += NW;
  bf16* qhp  = p; p += NQ;   // [B*H][T][64]
  bf16* khp  = p; p += NQ;   // [B*H][T][64]
  bf16* vtp  = p; p += NQ;   // [B*H][64][T]
  bf16* attn = p; p += NQ;   // [B][T][1024]

  cvt7<<<dim3(1024, 7, 1), 256, 0, stream>>>(q, k, v, Wq, Wk, Wv, Wo,
                                             qb, kb, vb, wqb, wkb, wvb, wob);
  qkv_gemm<<<dim3(32, 8, 3), 256, 0, stream>>>(qb, kb, vb, wqb, wkb, wvb,
                                               bq, bk, bv, qhp, khp, vtp);
  attn_fused<<<dim3(16, 32, 1), 256, 0, stream>>>(qhp, khp, vtp, attn);
  oproj_gemm<<<dim3(32, 8, 1), 256, 0, stream>>>(attn, wob, bo, (float*)d_out);
}

// Round 3
// 241.193 us; speedup vs baseline: 1.1733x; 1.1733x over previous
//
#include <hip/hip_runtime.h>
#include <cstdint>
#include <cstddef>

// ---------------------------------------------------------------------------
// MultiHeadAttention forward, MI355X/gfx950.
// cvt(fp32->bf16) -> fused QKV GEMM (MFMA) -> flash attention (S^T trick) ->
// output projection GEMM (fp32 out). All matmuls: v_mfma_f32_16x16x32_bf16.
// MFMA layouts (m89/m91/m120):
//   A-frag: lane l holds A[m = l&15][k = (l>>4)*8 + j], j=0..7
//   B-frag: lane l holds Bt[n = l&15][k = (l>>4)*8 + j]   (Bt = [N][K] row-major)
//   C/D   : lane l, reg r holds D[m = (l>>4)*4 + r][n = l&15]
// R2: attn computes S^T = MFMA(K_frag, Q_frag) so each lane owns 32 scores of
// its own query q=lr -> 2-shuffle reductions, bf16x4 packed P writes, and
// 8-wave/512-thread blocks for 16 waves/CU (was grid-capped at 8).
// ---------------------------------------------------------------------------

#define D_MODEL 1024
#define NHEAD   16
#define HDIM    64
#define BATCH   2
#define SEQ     2048
#define BT      (BATCH * SEQ)   // 4096

typedef __bf16 bf16;
typedef __bf16 bf16x8 __attribute__((ext_vector_type(8)));
typedef __bf16 bf16x4 __attribute__((ext_vector_type(4)));
typedef float  floatx4 __attribute__((ext_vector_type(4)));

#define MFMA16(a, b, c) __builtin_amdgcn_mfma_f32_16x16x32_bf16((a), (b), (c), 0, 0, 0)

// async global->LDS, 16B per lane. LDS dest = wave-uniform base + lane*16.
__device__ __forceinline__ void async_cp16(const bf16* g, bf16* l) {
  __builtin_amdgcn_global_load_lds(
      (__attribute__((address_space(1))) void*)(g),
      (__attribute__((address_space(3))) void*)(l), 16, 0, 0);
}

// ---------------------------------------------------------------------------
// fp32 -> bf16 conversion for q,k,v and the 4 weight matrices.
// ---------------------------------------------------------------------------
__global__ __launch_bounds__(256) void cvt7(
    const float* __restrict__ s0, const float* __restrict__ s1,
    const float* __restrict__ s2, const float* __restrict__ s3,
    const float* __restrict__ s4, const float* __restrict__ s5,
    const float* __restrict__ s6,
    bf16* __restrict__ d0, bf16* __restrict__ d1, bf16* __restrict__ d2,
    bf16* __restrict__ d3, bf16* __restrict__ d4, bf16* __restrict__ d5,
    bf16* __restrict__ d6)
{
  const float* src; bf16* dst; int n4;
  switch (blockIdx.y) {
    case 0:  src = s0; dst = d0; n4 = (BT * D_MODEL) / 4; break;
    case 1:  src = s1; dst = d1; n4 = (BT * D_MODEL) / 4; break;
    case 2:  src = s2; dst = d2; n4 = (BT * D_MODEL) / 4; break;
    case 3:  src = s3; dst = d3; n4 = (D_MODEL * D_MODEL) / 4; break;
    case 4:  src = s4; dst = d4; n4 = (D_MODEL * D_MODEL) / 4; break;
    case 5:  src = s5; dst = d5; n4 = (D_MODEL * D_MODEL) / 4; break;
    default: src = s6; dst = d6; n4 = (D_MODEL * D_MODEL) / 4; break;
  }
  int stride = gridDim.x * blockDim.x;
  for (int i = blockIdx.x * blockDim.x + threadIdx.x; i < n4; i += stride) {
    float4 f = ((const float4*)src)[i];
    bf16x4 h;
    h[0] = (bf16)f.x; h[1] = (bf16)f.y; h[2] = (bf16)f.z; h[3] = (bf16)f.w;
    ((bf16x4*)dst)[i] = h;
  }
}

// ---------------------------------------------------------------------------
// 128x128-tile GEMM core, K=1024, BK=32 (m97 structure).
// ---------------------------------------------------------------------------
__device__ __forceinline__ void gemm128_core(
    const bf16* __restrict__ A, const bf16* __restrict__ W,
    int m0, int n0, bf16* As, bf16* Bs, floatx4 acc[4][4])
{
  const int t = threadIdx.x;
  const int l = t & 63, w = t >> 6;
  const int quad = l >> 4, lr = l & 15;
  const int wm = (w >> 1) * 64, wn = (w & 1) * 64;

  floatx4 z = {0.f, 0.f, 0.f, 0.f};
#pragma unroll
  for (int i = 0; i < 4; i++)
#pragma unroll
    for (int j = 0; j < 4; j++) acc[i][j] = z;

  for (int kt = 0; kt < 1024; kt += 32) {
    __syncthreads();
#pragma unroll
    for (int i = 0; i < 2; i++) {
      int c = i * 256 + t;
      int row = c >> 2, ci = c & 3;
      async_cp16(A + (size_t)(m0 + row) * 1024 + kt + ci * 8,
                 As + (i * 256 + w * 64) * 8);
      async_cp16(W + (size_t)(n0 + row) * 1024 + kt + ci * 8,
                 Bs + (i * 256 + w * 64) * 8);
    }
    __syncthreads();

    bf16x8 af[4], bfr[4];
#pragma unroll
    for (int i = 0; i < 4; i++) {
      af[i]  = *(const bf16x8*)(As + (wm + i * 16 + lr) * 32 + quad * 8);
      bfr[i] = *(const bf16x8*)(Bs + (wn + i * 16 + lr) * 32 + quad * 8);
    }
#pragma unroll
    for (int i = 0; i < 4; i++)
#pragma unroll
      for (int j = 0; j < 4; j++)
        acc[i][j] = MFMA16(af[i], bfr[j], acc[i][j]);
  }
}

// ---------------------------------------------------------------------------
// Fused QKV projection. zid selects (q,Wq)->qh, (k,Wk)->kh, (v,Wv)->vt.
// qh,kh: [B*H][T][64]; v stored TRANSPOSED [B*H][64][T].
// ---------------------------------------------------------------------------
__global__ __launch_bounds__(256) void qkv_gemm(
    const bf16* __restrict__ qb, const bf16* __restrict__ kb, const bf16* __restrict__ vb,
    const bf16* __restrict__ wq, const bf16* __restrict__ wk, const bf16* __restrict__ wv,
    const float* __restrict__ biasq, const float* __restrict__ biask, const float* __restrict__ biasv,
    bf16* __restrict__ qh, bf16* __restrict__ kh, bf16* __restrict__ vt)
{
  __shared__ bf16 As[128 * 32];
  __shared__ bf16 Bs[128 * 32];
  const int zid = blockIdx.z;
  const bf16* A = (zid == 0) ? qb : ((zid == 1) ? kb : vb);
  const bf16* W = (zid == 0) ? wq : ((zid == 1) ? wk : wv);
  const float* bias = (zid == 0) ? biasq : ((zid == 1) ? biask : biasv);
  const int m0 = blockIdx.x * 128, n0 = blockIdx.y * 128;

  floatx4 acc[4][4];
  gemm128_core(A, W, m0, n0, As, Bs, acc);

  const int t = threadIdx.x, l = t & 63, w = t >> 6;
  const int quad = l >> 4, lr = l & 15;
  const int wm = (w >> 1) * 64, wn = (w & 1) * 64;

  if (zid < 2) {
    bf16* out = (zid == 0) ? qh : kh;
#pragma unroll
    for (int i = 0; i < 4; i++) {
      int mbase = m0 + wm + i * 16 + quad * 4;       // global row (b*2048+t)
      int b  = mbase >> 11;
      int tq = mbase & 2047;
#pragma unroll
      for (int j = 0; j < 4; j++) {
        int n = n0 + wn + j * 16 + lr;               // e = h*64 + dh
        float bv = bias[n];
        int h = n >> 6, dh = n & 63;
        bf16* p = out + ((size_t)((b * NHEAD + h) * SEQ + tq)) * HDIM + dh;
#pragma unroll
        for (int r = 0; r < 4; r++)
          p[(size_t)r * HDIM] = (bf16)(acc[i][j][r] + bv);
      }
    }
  } else {
#pragma unroll
    for (int i = 0; i < 4; i++) {
      int mbase = m0 + wm + i * 16 + quad * 4;
      int b  = mbase >> 11;
      int tq = mbase & 2047;
#pragma unroll
      for (int j = 0; j < 4; j++) {
        int n = n0 + wn + j * 16 + lr;
        float bv = bias[n];
        int h = n >> 6, dh = n & 63;
        bf16x4 pk;
#pragma unroll
        for (int r = 0; r < 4; r++) pk[r] = (bf16)(acc[i][j][r] + bv);
        *(bf16x4*)(vt + ((size_t)((b * NHEAD + h) * HDIM + dh)) * SEQ + tq) = pk;
      }
    }
  }
}

// ---------------------------------------------------------------------------
// Flash attention (S^T form). Grid: (T/128, B*H), block 512 = 8 waves; wave w
// owns 16 query rows. Per 128-key tile:
//   S^T tile = MFMA(K_frag, Q_frag): lane holds S[q=lr][key=ni*16+quad*4+r].
//   Row stats: in-register + shfl_xor(16,32). P: bf16x4 per ni (4 consecutive
//   keys) into per-wave LDS buffer, read back as A-frags (b128). PV via MFMA.
//   Oacc (C-layout rows quad*4+r) rescaled via 4 alpha-redistribution shfls.
// ---------------------------------------------------------------------------
__global__ __launch_bounds__(512, 4) void attn_fused(
    const bf16* __restrict__ qh, const bf16* __restrict__ kh,
    const bf16* __restrict__ vt, bf16* __restrict__ attn)
{
  __shared__ bf16 Ks[128 * 72];      // 18432 B
  __shared__ bf16 Vts[64 * 136];     // 17408 B
  __shared__ bf16 Pbuf[8 * 16 * 40]; // 10240 B; row stride 80 B (16B-aligned)

  const int t = threadIdx.x, l = t & 63, w = t >> 6;   // w in 0..7
  const int quad = l >> 4, lr = l & 15;
  const int bh = blockIdx.y;
  const int qt0 = blockIdx.x * 128;
  const bf16* qg = qh + (size_t)bh * SEQ * HDIM;
  const bf16* kg = kh + (size_t)bh * SEQ * HDIM;
  const bf16* vg = vt + (size_t)bh * HDIM * SEQ;

  // Q fragments (B-operand) for this wave's 16 rows: q = qt0 + w*16 + lr.
  bf16x8 qf[2];
#pragma unroll
  for (int ko = 0; ko < 2; ko++)
    qf[ko] = *(const bf16x8*)(qg + (size_t)(qt0 + w * 16 + lr) * HDIM
                              + ko * 32 + quad * 8);

  floatx4 zz = {0.f, 0.f, 0.f, 0.f};
  floatx4 Oacc[4];
#pragma unroll
  for (int di = 0; di < 4; di++) Oacc[di] = zz;
  float mrow = -3.0e38f, lrow = 0.f;
  const float scale = 0.125f;   // 1/sqrt(64)

  bf16* pw = Pbuf + w * 16 * 40;   // per-wave P buffer [16 q][32 keys + pad]

  for (int kt0 = 0; kt0 < SEQ; kt0 += 128) {
    __syncthreads();
    // Stage K-tile [128][64] and V^T-tile [64][128], 16B chunks, 512 threads.
#pragma unroll
    for (int i = 0; i < 2; i++) {
      int c = t + 512 * i;
      { int row = c >> 3, ci = c & 7;   // K: 8 chunks/row
        *(int4*)(Ks + row * 72 + ci * 8) =
            *(const int4*)(kg + (size_t)(kt0 + row) * HDIM + ci * 8); }
      { int row = c >> 4, ci = c & 15;  // V^T: 16 chunks/row
        *(int4*)(Vts + row * 136 + ci * 8) =
            *(const int4*)(vg + (size_t)row * SEQ + kt0 + ci * 8); }
    }
    __syncthreads();

    // S^T: lane holds S[q=lr][key = ni*16 + quad*4 + r], r=0..3, ni=0..7.
    floatx4 s[8];
#pragma unroll
    for (int ni = 0; ni < 8; ni++) {
      bf16x8 k0 = *(const bf16x8*)(Ks + (ni * 16 + lr) * 72 + quad * 8);
      bf16x8 k1 = *(const bf16x8*)(Ks + (ni * 16 + lr) * 72 + 32 + quad * 8);
      floatx4 a = zz;
      a = MFMA16(k0, qf[0], a);
      a = MFMA16(k1, qf[1], a);
      s[ni] = a;
    }

    // Row max over this tile's 128 keys for q = lr.
    float rmax = s[0][0];
#pragma unroll
    for (int ni = 0; ni < 8; ni++)
#pragma unroll
      for (int r = 0; r < 4; r++) rmax = fmaxf(rmax, s[ni][r]);
    rmax = fmaxf(rmax, __shfl_xor(rmax, 16, 64));
    rmax = fmaxf(rmax, __shfl_xor(rmax, 32, 64));

    float mnew  = fmaxf(mrow, rmax * scale);
    float alpha = __expf(mrow - mnew);
    mrow = mnew;

    // exp in place + row sum.
    float rsum = 0.f;
#pragma unroll
    for (int ni = 0; ni < 8; ni++)
#pragma unroll
      for (int r = 0; r < 4; r++) {
        float pv = __expf(s[ni][r] * scale - mnew);
        s[ni][r] = pv;
        rsum += pv;
      }
    rsum += __shfl_xor(rsum, 16, 64);
    rsum += __shfl_xor(rsum, 32, 64);
    lrow = lrow * alpha + rsum;

    // Rescale Oacc (rows m = quad*4+r) by alpha of query m: redistribute.
    float am[4];
#pragma unroll
    for (int r = 0; r < 4; r++)
      am[r] = __shfl(alpha, (l & 48) | (quad * 4 + r), 64);
#pragma unroll
    for (int di = 0; di < 4; di++)
#pragma unroll
      for (int r = 0; r < 4; r++) Oacc[di][r] *= am[r];

    // Stream P through per-wave LDS (32-key slices), PV MFMA.
#pragma unroll
    for (int kk = 0; kk < 4; kk++) {
#pragma unroll
      for (int jj = 0; jj < 2; jj++) {
        int ni = kk * 2 + jj;
        bf16x4 pk;
#pragma unroll
        for (int r = 0; r < 4; r++) pk[r] = (bf16)s[ni][r];
        *(bf16x4*)(pw + lr * 40 + jj * 16 + quad * 4) = pk;
      }
      bf16x8 pa = *(const bf16x8*)(pw + lr * 40 + quad * 8);
#pragma unroll
      for (int di = 0; di < 4; di++) {
        bf16x8 vfr = *(const bf16x8*)(Vts + (di * 16 + lr) * 136 + kk * 32 + quad * 8);
        Oacc[di] = MFMA16(pa, vfr, Oacc[di]);
      }
    }
  }

  // Epilogue: O /= l (redistribute 1/l to C-layout rows), store.
  float inv = 1.0f / lrow;
  float im[4];
#pragma unroll
  for (int r = 0; r < 4; r++)
    im[r] = __shfl(inv, (l & 48) | (quad * 4 + r), 64);
  const int b = bh >> 4, h = bh & 15;
#pragma unroll
  for (int di = 0; di < 4; di++)
#pragma unroll
    for (int r = 0; r < 4; r++) {
      int tq = qt0 + w * 16 + quad * 4 + r;
      attn[((size_t)b * SEQ + tq) * D_MODEL + h * HDIM + di * 16 + lr] =
          (bf16)(Oacc[di][r] * im[r]);
    }
}

// ---------------------------------------------------------------------------
// Output projection: out = attn @ Wo^T + bo, fp32 output.
// ---------------------------------------------------------------------------
__global__ __launch_bounds__(256) void oproj_gemm(
    const bf16* __restrict__ attn, const bf16* __restrict__ wo,
    const float* __restrict__ bo, float* __restrict__ out)
{
  __shared__ bf16 As[128 * 32];
  __shared__ bf16 Bs[128 * 32];
  const int m0 = blockIdx.x * 128, n0 = blockIdx.y * 128;

  floatx4 acc[4][4];
  gemm128_core(attn, wo, m0, n0, As, Bs, acc);

  const int t = threadIdx.x, l = t & 63, w = t >> 6;
  const int quad = l >> 4, lr = l & 15;
  const int wm = (w >> 1) * 64, wn = (w & 1) * 64;

#pragma unroll
  for (int i = 0; i < 4; i++) {
    int m = m0 + wm + i * 16 + quad * 4;
#pragma unroll
    for (int j = 0; j < 4; j++) {
      int n = n0 + wn + j * 16 + lr;
      float bv = bo[n];
      float* p = out + (size_t)m * D_MODEL + n;
#pragma unroll
      for (int r = 0; r < 4; r++)
        p[(size_t)r * D_MODEL] = acc[i][j][r] + bv;
    }
  }
}

// ---------------------------------------------------------------------------
extern "C" void kernel_launch(void* const* d_in, const int* in_sizes, int n_in,
                              void* d_out, int out_size, void* d_ws, size_t ws_size,
                              hipStream_t stream)
{
  const float* q  = (const float*)d_in[0];
  const float* k  = (const float*)d_in[1];
  const float* v  = (const float*)d_in[2];
  const float* Wq = (const float*)d_in[3];
  const float* bq = (const float*)d_in[4];
  const float* Wk = (const float*)d_in[5];
  const float* bk = (const float*)d_in[6];
  const float* Wv = (const float*)d_in[7];
  const float* bv = (const float*)d_in[8];
  const float* Wo = (const float*)d_in[9];
  const float* bo = (const float*)d_in[10];

  const size_t NQ = (size_t)BT * D_MODEL;        // 4194304
  const size_t NW = (size_t)D_MODEL * D_MODEL;   // 1048576

  bf16* p = (bf16*)d_ws;
  bf16* qb   = p; p += NQ;
  bf16* kb   = p; p += NQ;
  bf16* vb   = p; p += NQ;
  bf16* wqb  = p; p += NW;
  bf16* wkb  = p; p += NW;
  bf16* wvb  = p; p += NW;
  bf16* wob  = p; p += NW;
  bf16* qhp  = p; p += NQ;   // [B*H][T][64]
  bf16* khp  = p; p += NQ;   // [B*H][T][64]
  bf16* vtp  = p; p += NQ;   // [B*H][64][T]
  bf16* attn = p; p += NQ;   // [B][T][1024]

  cvt7<<<dim3(1024, 7, 1), 256, 0, stream>>>(q, k, v, Wq, Wk, Wv, Wo,
                                             qb, kb, vb, wqb, wkb, wvb, wob);
  qkv_gemm<<<dim3(32, 8, 3), 256, 0, stream>>>(qb, kb, vb, wqb, wkb, wvb,
                                               bq, bk, bv, qhp, khp, vtp);
  attn_fused<<<dim3(16, 32, 1), 512, 0, stream>>>(qhp, khp, vtp, attn);
  oproj_gemm<<<dim3(32, 8, 1), 256, 0, stream>>>(attn, wob, bo, (float*)d_out);
}